// Round 4
// baseline (732.122 us; speedup 1.0000x reference)
//
#include <hip/hip_runtime.h>
#include <hip/hip_bf16.h>
#include <math.h>
#include <stdint.h>

#define N_NODES 8192
#define E_EDGES 131072
#define D_DIM 128
#define M_EDGES (E_EDGES + N_NODES)
#define K_TOP 4096
#define NEG_SLOPE 0.2

// ---------------- edge init: row/col arrays + degree counts ----------------
__global__ void k_init_edges(const int* __restrict__ edge_src, const int* __restrict__ edge_off,
                             unsigned* __restrict__ rowA, unsigned* __restrict__ colA,
                             unsigned* __restrict__ dup,
                             unsigned* __restrict__ col_cnt, unsigned* __restrict__ row_cnt) {
    int e = blockIdx.x * blockDim.x + threadIdx.x;
    if (e >= M_EDGES) return;
    unsigned r, c;
    if (e < E_EDGES) {
        r = (unsigned)edge_src[e];
        c = (r + 1u + (unsigned)edge_off[e]) % N_NODES;
    } else {
        r = c = (unsigned)(e - E_EDGES);
    }
    rowA[e] = r; colA[e] = c; dup[e] = 0u;
    atomicAdd(&col_cnt[c], 1u);
    atomicAdd(&row_cnt[r], 1u);
}

// ---------------- dual single-block exclusive scan over 8192 counts ----------------
__global__ __launch_bounds__(1024) void k_scan2(const unsigned* __restrict__ cnt0, unsigned* __restrict__ off0, unsigned* __restrict__ cur0,
                                                const unsigned* __restrict__ cnt1, unsigned* __restrict__ off1, unsigned* __restrict__ cur1) {
    const unsigned* cnt = blockIdx.x ? cnt1 : cnt0;
    unsigned* off = blockIdx.x ? off1 : off0;
    unsigned* cur = blockIdx.x ? cur1 : cur0;
    __shared__ unsigned part[1024];
    const int n = N_NODES, per = N_NODES / 1024;
    int t = threadIdx.x;
    unsigned local[8];
    unsigned s = 0;
    for (int j = 0; j < per; j++) { local[j] = cnt[t * per + j]; s += local[j]; }
    part[t] = s; __syncthreads();
    for (int d = 1; d < 1024; d <<= 1) {
        unsigned v = (t >= d) ? part[t - d] : 0u;
        __syncthreads();
        part[t] += v;
        __syncthreads();
    }
    unsigned run = (t > 0) ? part[t - 1] : 0u;
    for (int j = 0; j < per; j++) {
        off[t * per + j] = run;
        if (cur) cur[t * per + j] = run;
        run += local[j];
    }
    if (t == 1023) off[n] = run;
}

// ---------------- CSR fill (atomic order; lists left unsorted) ----------------
__global__ void k_fill(const unsigned* __restrict__ rowA, const unsigned* __restrict__ colA,
                       unsigned* __restrict__ col_cur, unsigned* __restrict__ row_cur,
                       unsigned* __restrict__ col_edges, unsigned* __restrict__ row_edges) {
    int e = blockIdx.x * blockDim.x + threadIdx.x;
    if (e >= M_EDGES) return;
    unsigned p1 = atomicAdd(&col_cur[colA[e]], 1u); col_edges[p1] = (unsigned)e;
    unsigned p2 = atomicAdd(&row_cur[rowA[e]], 1u); row_edges[p2] = (unsigned)e;
}

// ---------------- fused: dup-mark + segment_max + x_q@W(LDS) + q/k scores ----
// 16 nodes per block, 128 threads, W staged once in 64 KB LDS.
__global__ __launch_bounds__(128) void k_lin(const float* __restrict__ x,
                                             const unsigned* __restrict__ col_off,
                                             const unsigned* __restrict__ col_edges,
                                             const unsigned* __restrict__ rowA,
                                             unsigned* __restrict__ dup,
                                             const float* __restrict__ W, const float* __restrict__ b_lin,
                                             const float* __restrict__ w_att,
                                             double* __restrict__ q_score, double* __restrict__ k_score) {
    __shared__ float Wlds[D_DIM * D_DIM];
    __shared__ float xq[D_DIM];
    __shared__ double red[4];
    int t = threadIdx.x;
    for (int idx = t; idx < D_DIM * D_DIM; idx += 128) Wlds[idx] = W[idx];
    double bl = (double)b_lin[t];
    double wq = (double)w_att[t];
    double wk = (double)w_att[D_DIM + t];
    __syncthreads();
    for (int nb = 0; nb < 16; nb++) {
        int c = blockIdx.x * 16 + nb;
        int lo = (int)col_off[c], hi = (int)col_off[c + 1];
        int n = hi - lo;
        // dup marking: mark all-but-one edge per duplicate (r,c) group
        for (int i = t; i < n; i += 128) {
            unsigned ri = rowA[col_edges[lo + i]];
            for (int j = 0; j < i; j++) {
                if (rowA[col_edges[lo + j]] == ri) { dup[col_edges[lo + i]] = 1u; break; }
            }
        }
        // segment max (each thread = one dim)
        float m = -INFINITY;
        for (int i = 0; i < n; i++) {
            unsigned r = rowA[col_edges[lo + i]];
            m = fmaxf(m, x[(size_t)r * D_DIM + t]);
        }
        xq[t] = m;
        __syncthreads();
        double acc = bl;
        for (int j = 0; j < D_DIM; j++) acc += (double)xq[j] * (double)Wlds[j * D_DIM + t];
        double q = acc * wq;
        double k = (double)x[(size_t)c * D_DIM + t] * wk;
        for (int o = 32; o > 0; o >>= 1) { q += __shfl_down(q, o); k += __shfl_down(k, o); }
        if ((t & 63) == 0) { red[t >> 6] = q; red[2 + (t >> 6)] = k; }
        __syncthreads();
        if (t == 0) { q_score[c] = red[0] + red[1]; k_score[c] = red[2] + red[3]; }
        __syncthreads();
    }
}

// ---------------- fused: per-col softmax (f64) + x_new + w1/w2/w3 dots ------
__global__ __launch_bounds__(128) void k_sm_xnew(const float* __restrict__ x,
                                                 const unsigned* __restrict__ col_off,
                                                 const unsigned* __restrict__ col_edges,
                                                 const unsigned* __restrict__ rowA,
                                                 const double* __restrict__ q_score,
                                                 const double* __restrict__ k_score,
                                                 const float* __restrict__ b_att,
                                                 const float* __restrict__ w1, const float* __restrict__ b1,
                                                 const float* __restrict__ w2, const float* __restrict__ w3,
                                                 const float* __restrict__ b3,
                                                 double* __restrict__ score_d, float* __restrict__ score_f,
                                                 float* __restrict__ x_new, double* __restrict__ aV,
                                                 double* __restrict__ bV, double* __restrict__ finV) {
    int c = blockIdx.x, t = threadIdx.x;
    __shared__ unsigned eloc[256];
    __shared__ unsigned rloc[256];
    __shared__ double sloc[256];
    __shared__ double redd[2];
    __shared__ double red6[6];
    int lo = (int)col_off[c], hi = (int)col_off[c + 1];
    int n = hi - lo;
    for (int i = t; i < n && i < 256; i += 128) {
        unsigned e = col_edges[lo + i];
        eloc[i] = e;
        rloc[i] = rowA[e];
    }
    __syncthreads();
    double qc = q_score[c] + (double)b_att[0];
    // --- max ---
    double m = -INFINITY;
    for (int i = t; i < n; i += 128) {
        unsigned r = (i < 256) ? rloc[i] : rowA[col_edges[lo + i]];
        double s = qc + k_score[r];
        s = (s >= 0.0) ? s : NEG_SLOPE * s;
        m = fmax(m, s);
    }
    for (int o = 32; o > 0; o >>= 1) m = fmax(m, __shfl_xor(m, o));
    if ((t & 63) == 0) redd[t >> 6] = m;
    __syncthreads();
    m = fmax(redd[0], redd[1]);
    __syncthreads();
    // --- sum ---
    double sum = 0.0;
    for (int i = t; i < n; i += 128) {
        unsigned r = (i < 256) ? rloc[i] : rowA[col_edges[lo + i]];
        double s = qc + k_score[r];
        s = (s >= 0.0) ? s : NEG_SLOPE * s;
        sum += exp(s - m);
    }
    for (int o = 32; o > 0; o >>= 1) sum += __shfl_xor(sum, o);
    if ((t & 63) == 0) redd[t >> 6] = sum;
    __syncthreads();
    sum = redd[0] + redd[1];
    // --- scores ---
    for (int i = t; i < n; i += 128) {
        unsigned e = (i < 256) ? eloc[i] : col_edges[lo + i];
        unsigned r = (i < 256) ? rloc[i] : rowA[e];
        double s = qc + k_score[r];
        s = (s >= 0.0) ? s : NEG_SLOPE * s;
        double w = exp(s - m) / sum;
        if (i < 256) sloc[i] = w;
        score_d[e] = w;
        score_f[e] = (float)w;
    }
    __syncthreads();
    // --- x_new ---
    int d = t;
    double acc = 0.0;
    for (int i = 0; i < n; i++) {
        unsigned r;
        double sc;
        if (i < 256) { r = rloc[i]; sc = sloc[i]; }
        else { unsigned e = col_edges[lo + i]; r = rowA[e]; sc = score_d[e]; }
        acc += sc * (double)x[(size_t)r * D_DIM + d];
    }
    x_new[(size_t)c * D_DIM + d] = (float)acc;
    double pa = acc * (double)w1[d], pb = acc * (double)w2[d], pf = acc * (double)w3[d];
    for (int o = 32; o > 0; o >>= 1) { pa += __shfl_down(pa, o); pb += __shfl_down(pb, o); pf += __shfl_down(pf, o); }
    if ((d & 63) == 0) { int w = d >> 6; red6[w] = pa; red6[2 + w] = pb; red6[4 + w] = pf; }
    __syncthreads();
    if (d == 0) {
        aV[c] = red6[0] + red6[1] + (double)b1[0];
        bV[c] = red6[2] + red6[3];
        finV[c] = red6[4] + red6[5] + (double)b3[0];
    }
}

// ---------------- fused: fitness + local bitonic sort of 2048 keys ----------
// key = (~orderable(f64 fitness) & ~0x1FFF) | node idx; ascending == stable argsort(-fitness)
__global__ __launch_bounds__(1024) void k_sortfit(const unsigned* __restrict__ col_off,
                                                  const unsigned* __restrict__ col_edges,
                                                  const unsigned* __restrict__ rowA,
                                                  const double* __restrict__ aV, const double* __restrict__ bV,
                                                  const double* __restrict__ finV,
                                                  double* __restrict__ fitness,
                                                  unsigned long long* __restrict__ keys) {
    __shared__ unsigned long long k2[2048];
    int t = threadIdx.x, base = blockIdx.x * 2048;
    for (int u = 0; u < 2; u++) {
        int c = base + u * 1024 + t;
        int lo = (int)col_off[c], hi = (int)col_off[c + 1];
        double s = finV[c] + (double)(hi - lo) * aV[c];
        for (int i = lo; i < hi; i++) s -= bV[rowA[col_edges[i]]];
        double fit = 1.0 / (1.0 + exp(-s));
        fitness[c] = fit;
        unsigned long long bits = (unsigned long long)__double_as_longlong(fit);
        unsigned long long uo = (bits & 0x8000000000000000ull) ? ~bits : (bits | 0x8000000000000000ull);
        k2[u * 1024 + t] = (~uo & 0xFFFFFFFFFFFFE000ull) | (unsigned long long)c;
    }
    __syncthreads();
    for (int size = 2; size <= 2048; size <<= 1) {
        for (int stride = size >> 1; stride > 0; stride >>= 1) {
            int pos = 2 * t - (t & (stride - 1));
            bool asc = ((pos & size) == 0);
            unsigned long long A = k2[pos], B = k2[pos + stride];
            if ((A > B) == asc) { k2[pos] = B; k2[pos + stride] = A; }
            __syncthreads();
        }
    }
    for (int i = t; i < 2048; i += 1024) keys[base + i] = k2[i];
}

// ---------------- sort stage 2: parallel merge of adjacent runs ----------------
__global__ __launch_bounds__(256) void k_merge(const unsigned long long* __restrict__ in,
                                               unsigned long long* __restrict__ out, int L) {
    int g = blockIdx.x * 256 + threadIdx.x;
    if (g >= N_NODES) return;
    int pair = g / (2 * L), r = g - pair * 2 * L;
    const unsigned long long* A = in + (size_t)pair * 2 * L;
    const unsigned long long* B = A + L;
    unsigned long long v; int p;
    if (r < L) {
        v = A[r];
        int lo = 0, hi = L;
        while (lo < hi) { int mid = (lo + hi) >> 1; if (B[mid] < v) lo = mid + 1; else hi = mid; }
        p = r + lo;
    } else {
        int j = r - L; v = B[j];
        int lo = 0, hi = L;
        while (lo < hi) { int mid = (lo + hi) >> 1; if (A[mid] < v) lo = mid + 1; else hi = mid; }
        p = j + lo;
    }
    out[(size_t)pair * 2 * L + p] = v;
}

// ---------------- sort stage 3: final merge, emit perm/inv ----------------
__global__ __launch_bounds__(256) void k_merge_emit(const unsigned long long* __restrict__ in,
                                                    unsigned* __restrict__ perm_i, int* __restrict__ inv_k,
                                                    float* __restrict__ perm_out) {
    int g = blockIdx.x * 256 + threadIdx.x;
    if (g >= N_NODES) return;
    const unsigned long long* A = in;
    const unsigned long long* B = in + 4096;
    unsigned long long v; int p;
    if (g < 4096) {
        v = A[g];
        int lo = 0, hi = 4096;
        while (lo < hi) { int mid = (lo + hi) >> 1; if (B[mid] < v) lo = mid + 1; else hi = mid; }
        p = g + lo;
    } else {
        int j = g - 4096; v = B[j];
        int lo = 0, hi = 4096;
        while (lo < hi) { int mid = (lo + hi) >> 1; if (A[mid] < v) lo = mid + 1; else hi = mid; }
        p = j + lo;
    }
    unsigned idx = (unsigned)(v & 0x1FFFull);
    inv_k[idx] = (p < K_TOP) ? p : -1;
    if (p < K_TOP) { perm_i[p] = idx; perm_out[p] = (float)idx; }
}

// ---------------- fused outputs: S_perm rows | A_new rows | x_out ----------------
// blocks [0,8192): S_perm row; [8192,12288): A_new row; [12288,12320): x_out.
__global__ __launch_bounds__(256) void k_fused_out(const unsigned* __restrict__ col_off,
                                                   const unsigned* __restrict__ col_edges,
                                                   const unsigned* __restrict__ row_off,
                                                   const unsigned* __restrict__ row_edges,
                                                   const unsigned* __restrict__ rowA,
                                                   const unsigned* __restrict__ colA,
                                                   const unsigned* __restrict__ dup,
                                                   const float* __restrict__ score,
                                                   const int* __restrict__ inv_k,
                                                   const unsigned* __restrict__ perm_i,
                                                   const float* __restrict__ x_new,
                                                   const double* __restrict__ fitness,
                                                   float* __restrict__ S_out,
                                                   float* __restrict__ A_out,
                                                   float* __restrict__ xo) {
    __shared__ float acc[K_TOP];
    __shared__ unsigned nloc[64];
    __shared__ float scloc[64];
    int bid = blockIdx.x, t = threadIdx.x;
    if (bid < N_NODES) {
        // ---- S_perm row: zero then scatter filtered out-edges ----
        int r = bid;
        float4* row4 = (float4*)(S_out + (size_t)r * K_TOP);
        float4 z; z.x = 0.f; z.y = 0.f; z.z = 0.f; z.w = 0.f;
        for (int i = t; i < K_TOP / 4; i += 256) row4[i] = z;
        __syncthreads();
        int lo = (int)row_off[r], hi = (int)row_off[r + 1];
        for (int j = lo + t; j < hi; j += 256) {
            unsigned e = row_edges[j];
            if (!dup[e]) {
                int kk = inv_k[colA[e]];
                if (kk >= 0) S_out[(size_t)r * K_TOP + kk] = score[e];
            }
        }
    } else if (bid < N_NODES + K_TOP) {
        // ---- A_new row k1: triple loop, LDS accumulator ----
        int k1 = bid - N_NODES;
        for (int i = t; i < K_TOP; i += 256) acc[i] = 0.f;
        unsigned p = perm_i[k1];
        int lo = (int)col_off[p], hi = (int)col_off[p + 1];
        for (int c0 = lo; c0 < hi; c0 += 64) {
            int nin = hi - c0; if (nin > 64) nin = 64;
            __syncthreads();
            if (t < nin) {
                unsigned e = col_edges[c0 + t];
                nloc[t] = dup[e] ? 0xFFFFFFFFu : rowA[e];
                scloc[t] = score[e];
            }
            __syncthreads();
            int g = t >> 3, lane = t & 7;   // 32 groups of 8
            for (int i = g; i < nin; i += 32) {
                unsigned n = nloc[i];
                if (n == 0xFFFFFFFFu) continue;
                float sc = scloc[i];
                int rlo = (int)row_off[n], rhi = (int)row_off[n + 1];
                for (int j = rlo + lane; j < rhi; j += 8) {
                    unsigned c2 = colA[row_edges[j]];
                    int qlo = (int)row_off[c2], qhi = (int)row_off[c2 + 1];
                    for (int q = qlo; q < qhi; q++) {
                        unsigned e3 = row_edges[q];
                        if (dup[e3]) continue;
                        int kk = inv_k[colA[e3]];
                        if (kk >= 0) atomicAdd(&acc[kk], sc * score[e3]);
                    }
                }
            }
        }
        __syncthreads();
        float* outp = &A_out[(size_t)k1 * K_TOP];
        for (int i = t; i < K_TOP; i += 256) outp[i] = (i == k1) ? 0.f : acc[i];
    } else {
        // ---- x_out ----
        int gid = (bid - N_NODES - K_TOP) * 256 + t;
        for (int u = gid; u < K_TOP * D_DIM; u += 32 * 256) {
            int k = u >> 7, d = u & 127;
            unsigned pp = perm_i[k];
            xo[u] = x_new[(size_t)pp * D_DIM + d] * (float)fitness[pp];
        }
    }
}

extern "C" void kernel_launch(void* const* d_in, const int* in_sizes, int n_in,
                              void* d_out, int out_size, void* d_ws, size_t ws_size,
                              hipStream_t stream) {
    const float* x        = (const float*)d_in[0];
    const int*   edge_src = (const int*)d_in[1];
    const int*   edge_off = (const int*)d_in[2];
    const float* W_lin    = (const float*)d_in[3];
    const float* b_lin    = (const float*)d_in[4];
    const float* w_att    = (const float*)d_in[5];
    const float* b_att    = (const float*)d_in[6];
    const float* w1       = (const float*)d_in[7];
    const float* b1       = (const float*)d_in[8];
    const float* w2       = (const float*)d_in[9];
    const float* w3       = (const float*)d_in[10];
    const float* b3       = (const float*)d_in[11];

    float* out = (float*)d_out;
    float* out_xout  = out;
    float* out_anew  = out + (size_t)K_TOP * D_DIM;
    float* out_perm  = out_anew + (size_t)K_TOP * K_TOP;
    float* out_sperm = out_perm + K_TOP;

    char* wp = (char*)d_ws;
    auto alloc = [&](size_t bytes) -> void* {
        void* p = (void*)wp;
        wp += (bytes + 255) & ~(size_t)255;
        return p;
    };
    unsigned* rowA      = (unsigned*)alloc((size_t)M_EDGES * 4);
    unsigned* colA      = (unsigned*)alloc((size_t)M_EDGES * 4);
    unsigned* dup       = (unsigned*)alloc((size_t)M_EDGES * 4);
    double*   score_d   = (double*)alloc((size_t)M_EDGES * 8);
    float*    score     = (float*)alloc((size_t)M_EDGES * 4);
    unsigned* cnts      = (unsigned*)alloc((size_t)2 * N_NODES * 4);
    unsigned* col_cnt   = cnts;
    unsigned* row_cnt   = cnts + N_NODES;
    unsigned* col_off   = (unsigned*)alloc((size_t)(N_NODES + 1) * 4);
    unsigned* row_off   = (unsigned*)alloc((size_t)(N_NODES + 1) * 4);
    unsigned* col_cur   = (unsigned*)alloc((size_t)N_NODES * 4);
    unsigned* row_cur   = (unsigned*)alloc((size_t)N_NODES * 4);
    unsigned* col_edges = (unsigned*)alloc((size_t)M_EDGES * 4);
    unsigned* row_edges = (unsigned*)alloc((size_t)M_EDGES * 4);
    float*    x_new     = (float*)alloc((size_t)N_NODES * D_DIM * 4);
    double*   q_score   = (double*)alloc((size_t)N_NODES * 8);
    double*   k_score   = (double*)alloc((size_t)N_NODES * 8);
    double*   aV        = (double*)alloc((size_t)N_NODES * 8);
    double*   bV        = (double*)alloc((size_t)N_NODES * 8);
    double*   finV      = (double*)alloc((size_t)N_NODES * 8);
    double*   fitness   = (double*)alloc((size_t)N_NODES * 8);
    unsigned long long* keys_a = (unsigned long long*)alloc((size_t)N_NODES * 8);
    unsigned long long* keys_b = (unsigned long long*)alloc((size_t)N_NODES * 8);
    unsigned* perm_i    = (unsigned*)alloc((size_t)K_TOP * 4);
    int*      inv_k     = (int*)alloc((size_t)N_NODES * 4);

    hipMemsetAsync(cnts, 0, (size_t)2 * N_NODES * 4, stream);

    k_init_edges<<<(M_EDGES + 255) / 256, 256, 0, stream>>>(edge_src, edge_off, rowA, colA, dup, col_cnt, row_cnt);
    k_scan2<<<2, 1024, 0, stream>>>(col_cnt, col_off, col_cur, row_cnt, row_off, row_cur);
    k_fill<<<(M_EDGES + 255) / 256, 256, 0, stream>>>(rowA, colA, col_cur, row_cur, col_edges, row_edges);
    k_lin<<<N_NODES / 16, 128, 0, stream>>>(x, col_off, col_edges, rowA, dup, W_lin, b_lin, w_att, q_score, k_score);
    k_sm_xnew<<<N_NODES, 128, 0, stream>>>(x, col_off, col_edges, rowA, q_score, k_score, b_att,
                                           w1, b1, w2, w3, b3, score_d, score, x_new, aV, bV, finV);
    k_sortfit<<<4, 1024, 0, stream>>>(col_off, col_edges, rowA, aV, bV, finV, fitness, keys_a);
    k_merge<<<N_NODES / 256, 256, 0, stream>>>(keys_a, keys_b, 2048);
    k_merge_emit<<<N_NODES / 256, 256, 0, stream>>>(keys_b, perm_i, inv_k, out_perm);
    k_fused_out<<<N_NODES + K_TOP + 32, 256, 0, stream>>>(col_off, col_edges, row_off, row_edges,
                                                          rowA, colA, dup, score, inv_k, perm_i,
                                                          x_new, fitness, out_sperm, out_anew, out_xout);
}

// Round 5
// 340.638 us; speedup vs baseline: 2.1493x; 2.1493x over previous
//
#include <hip/hip_runtime.h>
#include <hip/hip_bf16.h>
#include <math.h>
#include <stdint.h>

#define N_NODES 8192
#define E_EDGES 131072
#define D_DIM 128
#define M_EDGES (E_EDGES + N_NODES)
#define K_TOP 4096
#define NEG_SLOPE 0.2

// ---------------- edge init: row/col arrays + degree counts ----------------
__global__ void k_init_edges(const int* __restrict__ edge_src, const int* __restrict__ edge_off,
                             unsigned* __restrict__ rowA, unsigned* __restrict__ colA,
                             unsigned* __restrict__ dup,
                             unsigned* __restrict__ col_cnt, unsigned* __restrict__ row_cnt) {
    int e = blockIdx.x * blockDim.x + threadIdx.x;
    if (e >= M_EDGES) return;
    unsigned r, c;
    if (e < E_EDGES) {
        r = (unsigned)edge_src[e];
        c = (r + 1u + (unsigned)edge_off[e]) % N_NODES;
    } else {
        r = c = (unsigned)(e - E_EDGES);
    }
    rowA[e] = r; colA[e] = c; dup[e] = 0u;
    atomicAdd(&col_cnt[c], 1u);
    atomicAdd(&row_cnt[r], 1u);
}

// ---------------- dual single-block exclusive scan over 8192 counts ----------------
__global__ __launch_bounds__(1024) void k_scan2(const unsigned* __restrict__ cnt0, unsigned* __restrict__ off0, unsigned* __restrict__ cur0,
                                                const unsigned* __restrict__ cnt1, unsigned* __restrict__ off1, unsigned* __restrict__ cur1) {
    const unsigned* cnt = blockIdx.x ? cnt1 : cnt0;
    unsigned* off = blockIdx.x ? off1 : off0;
    unsigned* cur = blockIdx.x ? cur1 : cur0;
    __shared__ unsigned part[1024];
    const int n = N_NODES, per = N_NODES / 1024;
    int t = threadIdx.x;
    unsigned local[8];
    unsigned s = 0;
    for (int j = 0; j < per; j++) { local[j] = cnt[t * per + j]; s += local[j]; }
    part[t] = s; __syncthreads();
    for (int d = 1; d < 1024; d <<= 1) {
        unsigned v = (t >= d) ? part[t - d] : 0u;
        __syncthreads();
        part[t] += v;
        __syncthreads();
    }
    unsigned run = (t > 0) ? part[t - 1] : 0u;
    for (int j = 0; j < per; j++) {
        off[t * per + j] = run;
        if (cur) cur[t * per + j] = run;
        run += local[j];
    }
    if (t == 1023) off[n] = run;
}

// ---------------- CSR fill (atomic order; lists unsorted — values are order-invariant) --------
__global__ void k_fill(const unsigned* __restrict__ rowA, const unsigned* __restrict__ colA,
                       unsigned* __restrict__ col_cur, unsigned* __restrict__ row_cur,
                       unsigned* __restrict__ col_edges, unsigned* __restrict__ row_edges) {
    int e = blockIdx.x * blockDim.x + threadIdx.x;
    if (e >= M_EDGES) return;
    unsigned p1 = atomicAdd(&col_cur[colA[e]], 1u); col_edges[p1] = (unsigned)e;
    unsigned p2 = atomicAdd(&row_cur[rowA[e]], 1u); row_edges[p2] = (unsigned)e;
}

// ---------------- fused per-node: dup-mark + segment_max + x_q@W + q/k scores ----
__global__ __launch_bounds__(128) void k_lin(const float* __restrict__ x,
                                             const unsigned* __restrict__ col_off,
                                             const unsigned* __restrict__ col_edges,
                                             const unsigned* __restrict__ rowA,
                                             unsigned* __restrict__ dup,
                                             const float* __restrict__ W, const float* __restrict__ b_lin,
                                             const float* __restrict__ w_att,
                                             double* __restrict__ q_score, double* __restrict__ k_score) {
    int c = blockIdx.x, t = threadIdx.x;
    __shared__ unsigned rloc[256];
    __shared__ float xq[128];
    __shared__ double red[4];
    int lo = (int)col_off[c], hi = (int)col_off[c + 1];
    int n = hi - lo;
    for (int i = t; i < n && i < 256; i += 128) rloc[i] = rowA[col_edges[lo + i]];
    __syncthreads();
    // dup marking: any edge with an earlier-in-list same-row edge (representative arbitrary;
    // duplicate (r,c) edges carry identical scores so the choice is value-neutral)
    for (int i = t; i < n; i += 128) {
        unsigned ri = (i < 256) ? rloc[i] : rowA[col_edges[lo + i]];
        for (int j = 0; j < i; j++) {
            unsigned rj = (j < 256) ? rloc[j] : rowA[col_edges[lo + j]];
            if (rj == ri) { dup[col_edges[lo + i]] = 1u; break; }
        }
    }
    // segment max (thread = dim)
    float m = -INFINITY;
    for (int i = 0; i < n; i++) {
        unsigned r = (i < 256) ? rloc[i] : rowA[col_edges[lo + i]];
        m = fmaxf(m, x[(size_t)r * D_DIM + t]);
    }
    xq[t] = m;
    __syncthreads();
    double acc = (double)b_lin[t];
    for (int j = 0; j < D_DIM; j++) acc += (double)xq[j] * (double)W[j * D_DIM + t];
    double q = acc * (double)w_att[t];
    double k = (double)x[(size_t)c * D_DIM + t] * (double)w_att[D_DIM + t];
    for (int o = 32; o > 0; o >>= 1) { q += __shfl_down(q, o); k += __shfl_down(k, o); }
    if ((t & 63) == 0) { red[t >> 6] = q; red[2 + (t >> 6)] = k; }
    __syncthreads();
    if (t == 0) { q_score[c] = red[0] + red[1]; k_score[c] = red[2] + red[3]; }
}

// ---------------- fused: per-col softmax (f64) + x_new + w1/w2/w3 dots ------
__global__ __launch_bounds__(128) void k_sm_xnew(const float* __restrict__ x,
                                                 const unsigned* __restrict__ col_off,
                                                 const unsigned* __restrict__ col_edges,
                                                 const unsigned* __restrict__ rowA,
                                                 const double* __restrict__ q_score,
                                                 const double* __restrict__ k_score,
                                                 const float* __restrict__ b_att,
                                                 const float* __restrict__ w1, const float* __restrict__ b1,
                                                 const float* __restrict__ w2, const float* __restrict__ w3,
                                                 const float* __restrict__ b3,
                                                 double* __restrict__ score_d, float* __restrict__ score_f,
                                                 float* __restrict__ x_new, double* __restrict__ aV,
                                                 double* __restrict__ bV, double* __restrict__ finV) {
    int c = blockIdx.x, t = threadIdx.x;
    __shared__ unsigned eloc[256];
    __shared__ unsigned rloc[256];
    __shared__ double sloc[256];
    __shared__ double redd[2];
    __shared__ double red6[6];
    int lo = (int)col_off[c], hi = (int)col_off[c + 1];
    int n = hi - lo;
    for (int i = t; i < n && i < 256; i += 128) {
        unsigned e = col_edges[lo + i];
        eloc[i] = e;
        rloc[i] = rowA[e];
    }
    __syncthreads();
    double qc = q_score[c] + (double)b_att[0];
    // --- max ---
    double m = -INFINITY;
    for (int i = t; i < n; i += 128) {
        unsigned r = (i < 256) ? rloc[i] : rowA[col_edges[lo + i]];
        double s = qc + k_score[r];
        s = (s >= 0.0) ? s : NEG_SLOPE * s;
        m = fmax(m, s);
    }
    for (int o = 32; o > 0; o >>= 1) m = fmax(m, __shfl_xor(m, o));
    if ((t & 63) == 0) redd[t >> 6] = m;
    __syncthreads();
    m = fmax(redd[0], redd[1]);
    __syncthreads();
    // --- sum ---
    double sum = 0.0;
    for (int i = t; i < n; i += 128) {
        unsigned r = (i < 256) ? rloc[i] : rowA[col_edges[lo + i]];
        double s = qc + k_score[r];
        s = (s >= 0.0) ? s : NEG_SLOPE * s;
        sum += exp(s - m);
    }
    for (int o = 32; o > 0; o >>= 1) sum += __shfl_xor(sum, o);
    if ((t & 63) == 0) redd[t >> 6] = sum;
    __syncthreads();
    sum = redd[0] + redd[1];
    // --- scores ---
    for (int i = t; i < n; i += 128) {
        unsigned e = (i < 256) ? eloc[i] : col_edges[lo + i];
        unsigned r = (i < 256) ? rloc[i] : rowA[e];
        double s = qc + k_score[r];
        s = (s >= 0.0) ? s : NEG_SLOPE * s;
        double w = exp(s - m) / sum;
        if (i < 256) sloc[i] = w;
        score_d[e] = w;
        score_f[e] = (float)w;
    }
    __syncthreads();
    // --- x_new ---
    int d = t;
    double acc = 0.0;
    for (int i = 0; i < n; i++) {
        unsigned r;
        double sc;
        if (i < 256) { r = rloc[i]; sc = sloc[i]; }
        else { unsigned e = col_edges[lo + i]; r = rowA[e]; sc = score_d[e]; }
        acc += sc * (double)x[(size_t)r * D_DIM + d];
    }
    x_new[(size_t)c * D_DIM + d] = (float)acc;
    double pa = acc * (double)w1[d], pb = acc * (double)w2[d], pf = acc * (double)w3[d];
    for (int o = 32; o > 0; o >>= 1) { pa += __shfl_down(pa, o); pb += __shfl_down(pb, o); pf += __shfl_down(pf, o); }
    if ((d & 63) == 0) { int w = d >> 6; red6[w] = pa; red6[2 + w] = pb; red6[4 + w] = pf; }
    __syncthreads();
    if (d == 0) {
        aV[c] = red6[0] + red6[1] + (double)b1[0];
        bV[c] = red6[2] + red6[3];
        finV[c] = red6[4] + red6[5] + (double)b3[0];
    }
}

// ---------------- fused: fitness + local bitonic sort of 2048 keys ----------
// key = (~orderable(f64 fitness) & ~0x1FFF) | node idx; ascending == stable argsort(-fitness)
__global__ __launch_bounds__(1024) void k_sortfit(const unsigned* __restrict__ col_off,
                                                  const unsigned* __restrict__ col_edges,
                                                  const unsigned* __restrict__ rowA,
                                                  const double* __restrict__ aV, const double* __restrict__ bV,
                                                  const double* __restrict__ finV,
                                                  double* __restrict__ fitness,
                                                  unsigned long long* __restrict__ keys) {
    __shared__ unsigned long long k2[2048];
    int t = threadIdx.x, base = blockIdx.x * 2048;
    for (int u = 0; u < 2; u++) {
        int c = base + u * 1024 + t;
        int lo = (int)col_off[c], hi = (int)col_off[c + 1];
        double s = finV[c] + (double)(hi - lo) * aV[c];
        for (int i = lo; i < hi; i++) s -= bV[rowA[col_edges[i]]];
        double fit = 1.0 / (1.0 + exp(-s));
        fitness[c] = fit;
        unsigned long long bits = (unsigned long long)__double_as_longlong(fit);
        unsigned long long uo = (bits & 0x8000000000000000ull) ? ~bits : (bits | 0x8000000000000000ull);
        k2[u * 1024 + t] = (~uo & 0xFFFFFFFFFFFFE000ull) | (unsigned long long)c;
    }
    __syncthreads();
    for (int size = 2; size <= 2048; size <<= 1) {
        for (int stride = size >> 1; stride > 0; stride >>= 1) {
            int pos = 2 * t - (t & (stride - 1));
            bool asc = ((pos & size) == 0);
            unsigned long long A = k2[pos], B = k2[pos + stride];
            if ((A > B) == asc) { k2[pos] = B; k2[pos + stride] = A; }
            __syncthreads();
        }
    }
    for (int i = t; i < 2048; i += 1024) keys[base + i] = k2[i];
}

// ---------------- sort stage 2: parallel merge of adjacent runs ----------------
__global__ __launch_bounds__(256) void k_merge(const unsigned long long* __restrict__ in,
                                               unsigned long long* __restrict__ out, int L) {
    int g = blockIdx.x * 256 + threadIdx.x;
    if (g >= N_NODES) return;
    int pair = g / (2 * L), r = g - pair * 2 * L;
    const unsigned long long* A = in + (size_t)pair * 2 * L;
    const unsigned long long* B = A + L;
    unsigned long long v; int p;
    if (r < L) {
        v = A[r];
        int lo = 0, hi = L;
        while (lo < hi) { int mid = (lo + hi) >> 1; if (B[mid] < v) lo = mid + 1; else hi = mid; }
        p = r + lo;
    } else {
        int j = r - L; v = B[j];
        int lo = 0, hi = L;
        while (lo < hi) { int mid = (lo + hi) >> 1; if (A[mid] < v) lo = mid + 1; else hi = mid; }
        p = j + lo;
    }
    out[(size_t)pair * 2 * L + p] = v;
}

// ---------------- sort stage 3: final merge, emit perm/inv ----------------
__global__ __launch_bounds__(256) void k_merge_emit(const unsigned long long* __restrict__ in,
                                                    unsigned* __restrict__ perm_i, int* __restrict__ inv_k,
                                                    float* __restrict__ perm_out) {
    int g = blockIdx.x * 256 + threadIdx.x;
    if (g >= N_NODES) return;
    const unsigned long long* A = in;
    const unsigned long long* B = in + 4096;
    unsigned long long v; int p;
    if (g < 4096) {
        v = A[g];
        int lo = 0, hi = 4096;
        while (lo < hi) { int mid = (lo + hi) >> 1; if (B[mid] < v) lo = mid + 1; else hi = mid; }
        p = g + lo;
    } else {
        int j = g - 4096; v = B[j];
        int lo = 0, hi = 4096;
        while (lo < hi) { int mid = (lo + hi) >> 1; if (A[mid] < v) lo = mid + 1; else hi = mid; }
        p = j + lo;
    }
    unsigned idx = (unsigned)(v & 0x1FFFull);
    inv_k[idx] = (p < K_TOP) ? p : -1;
    if (p < K_TOP) { perm_i[p] = idx; perm_out[p] = (float)idx; }
}

// ---------------- S row lists (deduped out-edges landing in perm) ----------------
__global__ __launch_bounds__(64) void k_scount(const unsigned* __restrict__ row_off,
                                               const unsigned* __restrict__ row_edges,
                                               const unsigned* __restrict__ colA,
                                               const unsigned* __restrict__ dup,
                                               const int* __restrict__ inv_k,
                                               unsigned* __restrict__ s_cnt) {
    int c = blockIdx.x, t = threadIdx.x;
    int lo = (int)row_off[c], hi = (int)row_off[c + 1];
    unsigned cnt = 0;
    for (int i = lo + t; i < hi; i += 64) {
        unsigned e = row_edges[i];
        if (!dup[e] && inv_k[colA[e]] >= 0) cnt++;
    }
    for (int o = 32; o > 0; o >>= 1) cnt += __shfl_xor(cnt, o);
    if (t == 0) s_cnt[c] = cnt;
}

__global__ __launch_bounds__(64) void k_sfill(const unsigned* __restrict__ row_off,
                                              const unsigned* __restrict__ row_edges,
                                              const unsigned* __restrict__ colA,
                                              const unsigned* __restrict__ dup,
                                              const int* __restrict__ inv_k,
                                              const unsigned* __restrict__ s_off,
                                              const float* __restrict__ score,
                                              unsigned* __restrict__ s_k, float* __restrict__ s_v) {
    int c = blockIdx.x, t = threadIdx.x;
    int lo = (int)row_off[c], hi = (int)row_off[c + 1];
    unsigned base = s_off[c];
    for (int i0 = lo; i0 < hi; i0 += 64) {
        int i = i0 + t;
        bool pred = false; unsigned e = 0; int kk = -1;
        if (i < hi) {
            e = row_edges[i];
            kk = inv_k[colA[e]];
            pred = (!dup[e]) && (kk >= 0);
        }
        unsigned long long mask = __ballot(pred);
        if (pred) {
            unsigned pos = (unsigned)__popcll(mask & ((1ull << t) - 1ull));
            s_k[base + pos] = (unsigned)kk;
            s_v[base + pos] = score[e];
        }
        base += (unsigned)__popcll(mask);
    }
}

// ---------------- T row lists: per r, concat S-lists of all out-edge targets ----------------
__global__ __launch_bounds__(64) void k_tcount(const unsigned* __restrict__ row_off,
                                               const unsigned* __restrict__ row_edges,
                                               const unsigned* __restrict__ colA,
                                               const unsigned* __restrict__ s_cnt,
                                               unsigned* __restrict__ t_cnt) {
    int r = blockIdx.x, t = threadIdx.x;
    int lo = (int)row_off[r], hi = (int)row_off[r + 1];
    unsigned cnt = 0;
    for (int i = lo + t; i < hi; i += 64) cnt += s_cnt[colA[row_edges[i]]];
    for (int o = 32; o > 0; o >>= 1) cnt += __shfl_xor(cnt, o);
    if (t == 0) t_cnt[r] = cnt;
}

__global__ __launch_bounds__(64) void k_tfill(const unsigned* __restrict__ row_off,
                                              const unsigned* __restrict__ row_edges,
                                              const unsigned* __restrict__ colA,
                                              const unsigned* __restrict__ s_off,
                                              const unsigned* __restrict__ s_cnt,
                                              const unsigned* __restrict__ s_k,
                                              const float* __restrict__ s_v,
                                              const unsigned* __restrict__ t_off,
                                              unsigned* __restrict__ t_k, float* __restrict__ t_v,
                                              unsigned tcap) {
    int r = blockIdx.x, t = threadIdx.x;
    int lo = (int)row_off[r], hi = (int)row_off[r + 1];
    unsigned base = t_off[r];
    for (int i0 = lo; i0 < hi; i0 += 64) {
        int i = i0 + t;
        unsigned cnt = 0, c2 = 0;
        if (i < hi) { c2 = colA[row_edges[i]]; cnt = s_cnt[c2]; }
        unsigned pre = cnt;
        for (int o = 1; o < 64; o <<= 1) { unsigned v = __shfl_up(pre, o); if (t >= o) pre += v; }
        unsigned excl = pre - cnt;
        unsigned total = __shfl(pre, 63);
        if (i < hi && cnt) {
            unsigned sb = s_off[c2];
            unsigned db = base + excl;
            if (db + cnt <= tcap) {
                for (unsigned j = 0; j < cnt; j++) { t_k[db + j] = s_k[sb + j]; t_v[db + j] = s_v[sb + j]; }
            }
        }
        base += total;
    }
}

// ---------------- fused outputs: S_perm rows | A_new rows (T-lists) | x_out --------
// blocks [0,8192): S_perm row; [8192,12288): A_new row; [12288,12320): x_out.
__global__ __launch_bounds__(256) void k_fused_out(const unsigned* __restrict__ col_off,
                                                   const unsigned* __restrict__ col_edges,
                                                   const unsigned* __restrict__ row_off,
                                                   const unsigned* __restrict__ row_edges,
                                                   const unsigned* __restrict__ rowA,
                                                   const unsigned* __restrict__ colA,
                                                   const unsigned* __restrict__ dup,
                                                   const float* __restrict__ score,
                                                   const int* __restrict__ inv_k,
                                                   const unsigned* __restrict__ perm_i,
                                                   const unsigned* __restrict__ t_off,
                                                   const unsigned* __restrict__ t_k,
                                                   const float* __restrict__ t_v,
                                                   const float* __restrict__ x_new,
                                                   const double* __restrict__ fitness,
                                                   float* __restrict__ S_out,
                                                   float* __restrict__ A_out,
                                                   float* __restrict__ xo) {
    __shared__ float acc[K_TOP];
    int bid = blockIdx.x, t = threadIdx.x;
    if (bid < N_NODES) {
        // ---- S_perm row: zero then scatter filtered out-edges ----
        int r = bid;
        float4* row4 = (float4*)(S_out + (size_t)r * K_TOP);
        float4 z; z.x = 0.f; z.y = 0.f; z.z = 0.f; z.w = 0.f;
        for (int i = t; i < K_TOP / 4; i += 256) row4[i] = z;
        __syncthreads();
        int lo = (int)row_off[r], hi = (int)row_off[r + 1];
        for (int j = lo + t; j < hi; j += 256) {
            unsigned e = row_edges[j];
            if (!dup[e]) {
                int kk = inv_k[colA[e]];
                if (kk >= 0) S_out[(size_t)r * K_TOP + kk] = score[e];
            }
        }
    } else if (bid < N_NODES + K_TOP) {
        // ---- A_new row k1: stream T-lists of in-neighbors into LDS accumulator ----
        int k1 = bid - N_NODES;
        for (int i = t; i < K_TOP; i += 256) acc[i] = 0.f;
        __syncthreads();
        unsigned p = perm_i[k1];
        int lo = (int)col_off[p], hi = (int)col_off[p + 1];
        for (int i = lo; i < hi; i++) {
            unsigned e = col_edges[i];
            if (dup[e]) continue;
            float sc = score[e];
            unsigned n = rowA[e];
            unsigned tb = t_off[n], te = t_off[n + 1];
            for (unsigned j = tb + t; j < te; j += 256)
                atomicAdd(&acc[t_k[j]], sc * t_v[j]);
        }
        __syncthreads();
        float* outp = &A_out[(size_t)k1 * K_TOP];
        for (int i = t; i < K_TOP; i += 256) outp[i] = (i == k1) ? 0.f : acc[i];
    } else {
        // ---- x_out ----
        int gid = (bid - N_NODES - K_TOP) * 256 + t;
        for (int u = gid; u < K_TOP * D_DIM; u += 32 * 256) {
            int k = u >> 7, d = u & 127;
            unsigned pp = perm_i[k];
            xo[u] = x_new[(size_t)pp * D_DIM + d] * (float)fitness[pp];
        }
    }
}

extern "C" void kernel_launch(void* const* d_in, const int* in_sizes, int n_in,
                              void* d_out, int out_size, void* d_ws, size_t ws_size,
                              hipStream_t stream) {
    const float* x        = (const float*)d_in[0];
    const int*   edge_src = (const int*)d_in[1];
    const int*   edge_off = (const int*)d_in[2];
    const float* W_lin    = (const float*)d_in[3];
    const float* b_lin    = (const float*)d_in[4];
    const float* w_att    = (const float*)d_in[5];
    const float* b_att    = (const float*)d_in[6];
    const float* w1       = (const float*)d_in[7];
    const float* b1       = (const float*)d_in[8];
    const float* w2       = (const float*)d_in[9];
    const float* w3       = (const float*)d_in[10];
    const float* b3       = (const float*)d_in[11];

    float* out = (float*)d_out;
    float* out_xout  = out;
    float* out_anew  = out + (size_t)K_TOP * D_DIM;
    float* out_perm  = out_anew + (size_t)K_TOP * K_TOP;
    float* out_sperm = out_perm + K_TOP;

    char* wp = (char*)d_ws;
    char* wend = wp + ws_size;
    auto alloc = [&](size_t bytes) -> void* {
        void* p = (void*)wp;
        wp += (bytes + 255) & ~(size_t)255;
        return p;
    };
    unsigned* rowA      = (unsigned*)alloc((size_t)M_EDGES * 4);
    unsigned* colA      = (unsigned*)alloc((size_t)M_EDGES * 4);
    unsigned* dup       = (unsigned*)alloc((size_t)M_EDGES * 4);
    double*   score_d   = (double*)alloc((size_t)M_EDGES * 8);
    float*    score     = (float*)alloc((size_t)M_EDGES * 4);
    unsigned* cnts      = (unsigned*)alloc((size_t)2 * N_NODES * 4);
    unsigned* col_cnt   = cnts;
    unsigned* row_cnt   = cnts + N_NODES;
    unsigned* col_off   = (unsigned*)alloc((size_t)(N_NODES + 1) * 4);
    unsigned* row_off   = (unsigned*)alloc((size_t)(N_NODES + 1) * 4);
    unsigned* col_cur   = (unsigned*)alloc((size_t)N_NODES * 4);
    unsigned* row_cur   = (unsigned*)alloc((size_t)N_NODES * 4);
    unsigned* col_edges = (unsigned*)alloc((size_t)M_EDGES * 4);
    unsigned* row_edges = (unsigned*)alloc((size_t)M_EDGES * 4);
    float*    x_new     = (float*)alloc((size_t)N_NODES * D_DIM * 4);
    double*   q_score   = (double*)alloc((size_t)N_NODES * 8);
    double*   k_score   = (double*)alloc((size_t)N_NODES * 8);
    double*   aV        = (double*)alloc((size_t)N_NODES * 8);
    double*   bV        = (double*)alloc((size_t)N_NODES * 8);
    double*   finV      = (double*)alloc((size_t)N_NODES * 8);
    double*   fitness   = (double*)alloc((size_t)N_NODES * 8);
    unsigned long long* keys_a = (unsigned long long*)alloc((size_t)N_NODES * 8);
    unsigned long long* keys_b = (unsigned long long*)alloc((size_t)N_NODES * 8);
    unsigned* perm_i    = (unsigned*)alloc((size_t)K_TOP * 4);
    int*      inv_k     = (int*)alloc((size_t)N_NODES * 4);
    unsigned* s_cnt     = (unsigned*)alloc((size_t)N_NODES * 4);
    unsigned* s_off     = (unsigned*)alloc((size_t)(N_NODES + 1) * 4);
    unsigned* s_k       = (unsigned*)alloc((size_t)M_EDGES * 4);
    float*    s_v       = (float*)alloc((size_t)M_EDGES * 4);
    unsigned* t_cnt     = (unsigned*)alloc((size_t)N_NODES * 4);
    unsigned* t_off     = (unsigned*)alloc((size_t)(N_NODES + 1) * 4);
    size_t remain = (size_t)(wend - wp);
    size_t tcap = remain / 8;
    if (tcap > (size_t)6 * 1024 * 1024) tcap = (size_t)6 * 1024 * 1024;
    unsigned* t_k = (unsigned*)alloc(tcap * 4);
    float*    t_v = (float*)alloc(tcap * 4);

    hipMemsetAsync(cnts, 0, (size_t)2 * N_NODES * 4, stream);

    k_init_edges<<<(M_EDGES + 255) / 256, 256, 0, stream>>>(edge_src, edge_off, rowA, colA, dup, col_cnt, row_cnt);
    k_scan2<<<2, 1024, 0, stream>>>(col_cnt, col_off, col_cur, row_cnt, row_off, row_cur);
    k_fill<<<(M_EDGES + 255) / 256, 256, 0, stream>>>(rowA, colA, col_cur, row_cur, col_edges, row_edges);
    k_lin<<<N_NODES, 128, 0, stream>>>(x, col_off, col_edges, rowA, dup, W_lin, b_lin, w_att, q_score, k_score);
    k_sm_xnew<<<N_NODES, 128, 0, stream>>>(x, col_off, col_edges, rowA, q_score, k_score, b_att,
                                           w1, b1, w2, w3, b3, score_d, score, x_new, aV, bV, finV);
    k_sortfit<<<4, 1024, 0, stream>>>(col_off, col_edges, rowA, aV, bV, finV, fitness, keys_a);
    k_merge<<<N_NODES / 256, 256, 0, stream>>>(keys_a, keys_b, 2048);
    k_merge_emit<<<N_NODES / 256, 256, 0, stream>>>(keys_b, perm_i, inv_k, out_perm);
    k_scount<<<N_NODES, 64, 0, stream>>>(row_off, row_edges, colA, dup, inv_k, s_cnt);
    k_tcount<<<N_NODES, 64, 0, stream>>>(row_off, row_edges, colA, s_cnt, t_cnt);
    k_scan2<<<2, 1024, 0, stream>>>(s_cnt, s_off, (unsigned*)nullptr, t_cnt, t_off, (unsigned*)nullptr);
    k_sfill<<<N_NODES, 64, 0, stream>>>(row_off, row_edges, colA, dup, inv_k, s_off, score, s_k, s_v);
    k_tfill<<<N_NODES, 64, 0, stream>>>(row_off, row_edges, colA, s_off, s_cnt, s_k, s_v, t_off,
                                        t_k, t_v, (unsigned)tcap);
    k_fused_out<<<N_NODES + K_TOP + 32, 256, 0, stream>>>(col_off, col_edges, row_off, row_edges,
                                                          rowA, colA, dup, score, inv_k, perm_i,
                                                          t_off, t_k, t_v, x_new, fitness,
                                                          out_sperm, out_anew, out_xout);
}

// Round 6
// 277.179 us; speedup vs baseline: 2.6413x; 1.2289x over previous
//
#include <hip/hip_runtime.h>
#include <hip/hip_bf16.h>
#include <math.h>
#include <stdint.h>

#define N_NODES 8192
#define E_EDGES 131072
#define D_DIM 128
#define M_EDGES (E_EDGES + N_NODES)
#define K_TOP 4096
#define NEG_SLOPE 0.2

// ---------------- edge init: row/col arrays + degree counts ----------------
__global__ void k_init_edges(const int* __restrict__ edge_src, const int* __restrict__ edge_off,
                             unsigned* __restrict__ rowA, unsigned* __restrict__ colA,
                             unsigned* __restrict__ dup,
                             unsigned* __restrict__ col_cnt, unsigned* __restrict__ row_cnt) {
    int e = blockIdx.x * blockDim.x + threadIdx.x;
    if (e >= M_EDGES) return;
    unsigned r, c;
    if (e < E_EDGES) {
        r = (unsigned)edge_src[e];
        c = (r + 1u + (unsigned)edge_off[e]) % N_NODES;
    } else {
        r = c = (unsigned)(e - E_EDGES);
    }
    rowA[e] = r; colA[e] = c; dup[e] = 0u;
    atomicAdd(&col_cnt[c], 1u);
    atomicAdd(&row_cnt[r], 1u);
}

// ---------------- dual single-block exclusive scan over 8192 counts ----------------
__global__ __launch_bounds__(1024) void k_scan2(const unsigned* __restrict__ cnt0, unsigned* __restrict__ off0, unsigned* __restrict__ cur0,
                                                const unsigned* __restrict__ cnt1, unsigned* __restrict__ off1, unsigned* __restrict__ cur1) {
    const unsigned* cnt = blockIdx.x ? cnt1 : cnt0;
    unsigned* off = blockIdx.x ? off1 : off0;
    unsigned* cur = blockIdx.x ? cur1 : cur0;
    __shared__ unsigned part[1024];
    const int n = N_NODES, per = N_NODES / 1024;
    int t = threadIdx.x;
    unsigned local[8];
    unsigned s = 0;
    for (int j = 0; j < per; j++) { local[j] = cnt[t * per + j]; s += local[j]; }
    part[t] = s; __syncthreads();
    for (int d = 1; d < 1024; d <<= 1) {
        unsigned v = (t >= d) ? part[t - d] : 0u;
        __syncthreads();
        part[t] += v;
        __syncthreads();
    }
    unsigned run = (t > 0) ? part[t - 1] : 0u;
    for (int j = 0; j < per; j++) {
        off[t * per + j] = run;
        if (cur) cur[t * per + j] = run;
        run += local[j];
    }
    if (t == 1023) off[n] = run;
}

// ---------------- CSR fill (atomic order; lists unsorted — values order-invariant) ----
__global__ void k_fill(const unsigned* __restrict__ rowA, const unsigned* __restrict__ colA,
                       unsigned* __restrict__ col_cur, unsigned* __restrict__ row_cur,
                       unsigned* __restrict__ col_edges, unsigned* __restrict__ row_edges) {
    int e = blockIdx.x * blockDim.x + threadIdx.x;
    if (e >= M_EDGES) return;
    unsigned p1 = atomicAdd(&col_cur[colA[e]], 1u); col_edges[p1] = (unsigned)e;
    unsigned p2 = atomicAdd(&row_cur[rowA[e]], 1u); row_edges[p2] = (unsigned)e;
}

// ---------------- fused per-node: dup-mark + segment_max + x_q@W + q/k scores ----
__global__ __launch_bounds__(128) void k_lin(const float* __restrict__ x,
                                             const unsigned* __restrict__ col_off,
                                             const unsigned* __restrict__ col_edges,
                                             const unsigned* __restrict__ rowA,
                                             unsigned* __restrict__ dup,
                                             const float* __restrict__ W, const float* __restrict__ b_lin,
                                             const float* __restrict__ w_att,
                                             double* __restrict__ q_score, double* __restrict__ k_score) {
    int c = blockIdx.x, t = threadIdx.x;
    __shared__ unsigned rloc[256];
    __shared__ float xq[128];
    __shared__ double red[4];
    int lo = (int)col_off[c], hi = (int)col_off[c + 1];
    int n = hi - lo;
    for (int i = t; i < n && i < 256; i += 128) rloc[i] = rowA[col_edges[lo + i]];
    __syncthreads();
    // dup marking: any edge with an earlier-in-list same-row edge (duplicate (r,c)
    // edges carry identical scores, so representative choice is value-neutral)
    for (int i = t; i < n; i += 128) {
        unsigned ri = (i < 256) ? rloc[i] : rowA[col_edges[lo + i]];
        for (int j = 0; j < i; j++) {
            unsigned rj = (j < 256) ? rloc[j] : rowA[col_edges[lo + j]];
            if (rj == ri) { dup[col_edges[lo + i]] = 1u; break; }
        }
    }
    // segment max (thread = dim)
    float m = -INFINITY;
    for (int i = 0; i < n; i++) {
        unsigned r = (i < 256) ? rloc[i] : rowA[col_edges[lo + i]];
        m = fmaxf(m, x[(size_t)r * D_DIM + t]);
    }
    xq[t] = m;
    __syncthreads();
    double acc = (double)b_lin[t];
    for (int j = 0; j < D_DIM; j++) acc += (double)xq[j] * (double)W[j * D_DIM + t];
    double q = acc * (double)w_att[t];
    double k = (double)x[(size_t)c * D_DIM + t] * (double)w_att[D_DIM + t];
    for (int o = 32; o > 0; o >>= 1) { q += __shfl_down(q, o); k += __shfl_down(k, o); }
    if ((t & 63) == 0) { red[t >> 6] = q; red[2 + (t >> 6)] = k; }
    __syncthreads();
    if (t == 0) { q_score[c] = red[0] + red[1]; k_score[c] = red[2] + red[3]; }
}

// ---------------- fused: per-col softmax (f64) + x_new + w1/w2/w3 dots ------
__global__ __launch_bounds__(128) void k_sm_xnew(const float* __restrict__ x,
                                                 const unsigned* __restrict__ col_off,
                                                 const unsigned* __restrict__ col_edges,
                                                 const unsigned* __restrict__ rowA,
                                                 const double* __restrict__ q_score,
                                                 const double* __restrict__ k_score,
                                                 const float* __restrict__ b_att,
                                                 const float* __restrict__ w1, const float* __restrict__ b1,
                                                 const float* __restrict__ w2, const float* __restrict__ w3,
                                                 const float* __restrict__ b3,
                                                 double* __restrict__ score_d, float* __restrict__ score_f,
                                                 float* __restrict__ x_new, double* __restrict__ aV,
                                                 double* __restrict__ bV, double* __restrict__ finV) {
    int c = blockIdx.x, t = threadIdx.x;
    __shared__ unsigned eloc[256];
    __shared__ unsigned rloc[256];
    __shared__ double sloc[256];
    __shared__ double redd[2];
    __shared__ double red6[6];
    int lo = (int)col_off[c], hi = (int)col_off[c + 1];
    int n = hi - lo;
    for (int i = t; i < n && i < 256; i += 128) {
        unsigned e = col_edges[lo + i];
        eloc[i] = e;
        rloc[i] = rowA[e];
    }
    __syncthreads();
    double qc = q_score[c] + (double)b_att[0];
    // --- max ---
    double m = -INFINITY;
    for (int i = t; i < n; i += 128) {
        unsigned r = (i < 256) ? rloc[i] : rowA[col_edges[lo + i]];
        double s = qc + k_score[r];
        s = (s >= 0.0) ? s : NEG_SLOPE * s;
        m = fmax(m, s);
    }
    for (int o = 32; o > 0; o >>= 1) m = fmax(m, __shfl_xor(m, o));
    if ((t & 63) == 0) redd[t >> 6] = m;
    __syncthreads();
    m = fmax(redd[0], redd[1]);
    __syncthreads();
    // --- sum ---
    double sum = 0.0;
    for (int i = t; i < n; i += 128) {
        unsigned r = (i < 256) ? rloc[i] : rowA[col_edges[lo + i]];
        double s = qc + k_score[r];
        s = (s >= 0.0) ? s : NEG_SLOPE * s;
        sum += exp(s - m);
    }
    for (int o = 32; o > 0; o >>= 1) sum += __shfl_xor(sum, o);
    if ((t & 63) == 0) redd[t >> 6] = sum;
    __syncthreads();
    sum = redd[0] + redd[1];
    // --- scores ---
    for (int i = t; i < n; i += 128) {
        unsigned e = (i < 256) ? eloc[i] : col_edges[lo + i];
        unsigned r = (i < 256) ? rloc[i] : rowA[e];
        double s = qc + k_score[r];
        s = (s >= 0.0) ? s : NEG_SLOPE * s;
        double w = exp(s - m) / sum;
        if (i < 256) sloc[i] = w;
        score_d[e] = w;
        score_f[e] = (float)w;
    }
    __syncthreads();
    // --- x_new ---
    int d = t;
    double acc = 0.0;
    for (int i = 0; i < n; i++) {
        unsigned r;
        double sc;
        if (i < 256) { r = rloc[i]; sc = sloc[i]; }
        else { unsigned e = col_edges[lo + i]; r = rowA[e]; sc = score_d[e]; }
        acc += sc * (double)x[(size_t)r * D_DIM + d];
    }
    x_new[(size_t)c * D_DIM + d] = (float)acc;
    double pa = acc * (double)w1[d], pb = acc * (double)w2[d], pf = acc * (double)w3[d];
    for (int o = 32; o > 0; o >>= 1) { pa += __shfl_down(pa, o); pb += __shfl_down(pb, o); pf += __shfl_down(pf, o); }
    if ((d & 63) == 0) { int w = d >> 6; red6[w] = pa; red6[2 + w] = pb; red6[4 + w] = pf; }
    __syncthreads();
    if (d == 0) {
        aV[c] = red6[0] + red6[1] + (double)b1[0];
        bV[c] = red6[2] + red6[3];
        finV[c] = red6[4] + red6[5] + (double)b3[0];
    }
}

// ---------------- agg + fitness (f64), full-chip parallel ----------------
__global__ __launch_bounds__(64) void k_fitness(const unsigned* __restrict__ col_off,
                                                const unsigned* __restrict__ col_edges,
                                                const unsigned* __restrict__ rowA,
                                                const double* __restrict__ aV, const double* __restrict__ bV,
                                                const double* __restrict__ finV,
                                                double* __restrict__ fitness) {
    int c = blockIdx.x, t = threadIdx.x;
    int lo = (int)col_off[c], hi = (int)col_off[c + 1];
    double ac = aV[c], s = 0.0;
    for (int i = lo + t; i < hi; i += 64) s += ac - bV[rowA[col_edges[i]]];
    for (int o = 32; o > 0; o >>= 1) s += __shfl_xor(s, o);
    if (t == 0) {
        double z = finV[c] + s;
        fitness[c] = 1.0 / (1.0 + exp(-z));
    }
}

// ---------------- sort stage 1: 4 blocks sort 2048 keys each (ascending) ----------------
// key = (~orderable(f64 fitness) & ~0x1FFF) | node idx; ascending == stable argsort(-fitness)
__global__ __launch_bounds__(1024) void k_sortlocal(const double* __restrict__ fitness,
                                                    unsigned long long* __restrict__ keys) {
    __shared__ unsigned long long k2[2048];
    int t = threadIdx.x, base = blockIdx.x * 2048;
    for (int i = t; i < 2048; i += 1024) {
        unsigned long long bits = (unsigned long long)__double_as_longlong(fitness[base + i]);
        unsigned long long u = (bits & 0x8000000000000000ull) ? ~bits : (bits | 0x8000000000000000ull);
        k2[i] = (~u & 0xFFFFFFFFFFFFE000ull) | (unsigned long long)(base + i);
    }
    __syncthreads();
    for (int size = 2; size <= 2048; size <<= 1) {
        for (int stride = size >> 1; stride > 0; stride >>= 1) {
            int pos = 2 * t - (t & (stride - 1));
            bool asc = ((pos & size) == 0);
            unsigned long long A = k2[pos], B = k2[pos + stride];
            if ((A > B) == asc) { k2[pos] = B; k2[pos + stride] = A; }
            __syncthreads();
        }
    }
    for (int i = t; i < 2048; i += 1024) keys[base + i] = k2[i];
}

// ---------------- sort stage 2: parallel merge of adjacent runs ----------------
__global__ __launch_bounds__(256) void k_merge(const unsigned long long* __restrict__ in,
                                               unsigned long long* __restrict__ out, int L) {
    int g = blockIdx.x * 256 + threadIdx.x;
    if (g >= N_NODES) return;
    int pair = g / (2 * L), r = g - pair * 2 * L;
    const unsigned long long* A = in + (size_t)pair * 2 * L;
    const unsigned long long* B = A + L;
    unsigned long long v; int p;
    if (r < L) {
        v = A[r];
        int lo = 0, hi = L;
        while (lo < hi) { int mid = (lo + hi) >> 1; if (B[mid] < v) lo = mid + 1; else hi = mid; }
        p = r + lo;
    } else {
        int j = r - L; v = B[j];
        int lo = 0, hi = L;
        while (lo < hi) { int mid = (lo + hi) >> 1; if (A[mid] < v) lo = mid + 1; else hi = mid; }
        p = j + lo;
    }
    out[(size_t)pair * 2 * L + p] = v;
}

// ---------------- sort stage 3: final merge, emit perm/inv ----------------
__global__ __launch_bounds__(256) void k_merge_emit(const unsigned long long* __restrict__ in,
                                                    unsigned* __restrict__ perm_i, int* __restrict__ inv_k,
                                                    float* __restrict__ perm_out) {
    int g = blockIdx.x * 256 + threadIdx.x;
    if (g >= N_NODES) return;
    const unsigned long long* A = in;
    const unsigned long long* B = in + 4096;
    unsigned long long v; int p;
    if (g < 4096) {
        v = A[g];
        int lo = 0, hi = 4096;
        while (lo < hi) { int mid = (lo + hi) >> 1; if (B[mid] < v) lo = mid + 1; else hi = mid; }
        p = g + lo;
    } else {
        int j = g - 4096; v = B[j];
        int lo = 0, hi = 4096;
        while (lo < hi) { int mid = (lo + hi) >> 1; if (A[mid] < v) lo = mid + 1; else hi = mid; }
        p = j + lo;
    }
    unsigned idx = (unsigned)(v & 0x1FFFull);
    inv_k[idx] = (p < K_TOP) ? p : -1;
    if (p < K_TOP) { perm_i[p] = idx; perm_out[p] = (float)idx; }
}

// ---------------- S row lists (deduped out-edges landing in perm) ----------------
__global__ __launch_bounds__(64) void k_scount(const unsigned* __restrict__ row_off,
                                               const unsigned* __restrict__ row_edges,
                                               const unsigned* __restrict__ colA,
                                               const unsigned* __restrict__ dup,
                                               const int* __restrict__ inv_k,
                                               unsigned* __restrict__ s_cnt) {
    int c = blockIdx.x, t = threadIdx.x;
    int lo = (int)row_off[c], hi = (int)row_off[c + 1];
    unsigned cnt = 0;
    for (int i = lo + t; i < hi; i += 64) {
        unsigned e = row_edges[i];
        if (!dup[e] && inv_k[colA[e]] >= 0) cnt++;
    }
    for (int o = 32; o > 0; o >>= 1) cnt += __shfl_xor(cnt, o);
    if (t == 0) s_cnt[c] = cnt;
}

__global__ __launch_bounds__(64) void k_sfill(const unsigned* __restrict__ row_off,
                                              const unsigned* __restrict__ row_edges,
                                              const unsigned* __restrict__ colA,
                                              const unsigned* __restrict__ dup,
                                              const int* __restrict__ inv_k,
                                              const unsigned* __restrict__ s_off,
                                              const float* __restrict__ score,
                                              unsigned* __restrict__ s_k, float* __restrict__ s_v) {
    int c = blockIdx.x, t = threadIdx.x;
    int lo = (int)row_off[c], hi = (int)row_off[c + 1];
    unsigned base = s_off[c];
    for (int i0 = lo; i0 < hi; i0 += 64) {
        int i = i0 + t;
        bool pred = false; unsigned e = 0; int kk = -1;
        if (i < hi) {
            e = row_edges[i];
            kk = inv_k[colA[e]];
            pred = (!dup[e]) && (kk >= 0);
        }
        unsigned long long mask = __ballot(pred);
        if (pred) {
            unsigned pos = (unsigned)__popcll(mask & ((1ull << t) - 1ull));
            s_k[base + pos] = (unsigned)kk;
            s_v[base + pos] = score[e];
        }
        base += (unsigned)__popcll(mask);
    }
}

// ---------------- T row lists: per r, concat S-lists of all out-edge targets ----------------
__global__ __launch_bounds__(64) void k_tcount(const unsigned* __restrict__ row_off,
                                               const unsigned* __restrict__ row_edges,
                                               const unsigned* __restrict__ colA,
                                               const unsigned* __restrict__ s_cnt,
                                               unsigned* __restrict__ t_cnt) {
    int r = blockIdx.x, t = threadIdx.x;
    int lo = (int)row_off[r], hi = (int)row_off[r + 1];
    unsigned cnt = 0;
    for (int i = lo + t; i < hi; i += 64) cnt += s_cnt[colA[row_edges[i]]];
    for (int o = 32; o > 0; o >>= 1) cnt += __shfl_xor(cnt, o);
    if (t == 0) t_cnt[r] = cnt;
}

__global__ __launch_bounds__(64) void k_tfill(const unsigned* __restrict__ row_off,
                                              const unsigned* __restrict__ row_edges,
                                              const unsigned* __restrict__ colA,
                                              const unsigned* __restrict__ s_off,
                                              const unsigned* __restrict__ s_cnt,
                                              const unsigned* __restrict__ s_k,
                                              const float* __restrict__ s_v,
                                              const unsigned* __restrict__ t_off,
                                              unsigned* __restrict__ t_k, float* __restrict__ t_v,
                                              unsigned tcap) {
    int r = blockIdx.x, t = threadIdx.x;
    int lo = (int)row_off[r], hi = (int)row_off[r + 1];
    unsigned base = t_off[r];
    for (int i0 = lo; i0 < hi; i0 += 64) {
        int i = i0 + t;
        unsigned cnt = 0, c2 = 0;
        if (i < hi) { c2 = colA[row_edges[i]]; cnt = s_cnt[c2]; }
        unsigned pre = cnt;
        for (int o = 1; o < 64; o <<= 1) { unsigned v = __shfl_up(pre, o); if (t >= o) pre += v; }
        unsigned excl = pre - cnt;
        unsigned total = __shfl(pre, 63);
        if (i < hi && cnt) {
            unsigned sb = s_off[c2];
            unsigned db = base + excl;
            if (db + cnt <= tcap) {
                for (unsigned j = 0; j < cnt; j++) { t_k[db + j] = s_k[sb + j]; t_v[db + j] = s_v[sb + j]; }
            }
        }
        base += total;
    }
}

// ---------------- S_perm: fused zero + scatter, one row per block (no LDS) ----------------
__global__ __launch_bounds__(256) void k_spermz(const unsigned* __restrict__ s_off,
                                                const unsigned* __restrict__ s_k,
                                                const float* __restrict__ s_v,
                                                float* __restrict__ S_out) {
    int r = blockIdx.x, t = threadIdx.x;
    float4* row4 = (float4*)(S_out + (size_t)r * K_TOP);
    float4 z; z.x = 0.f; z.y = 0.f; z.z = 0.f; z.w = 0.f;
    for (int i = t; i < K_TOP / 4; i += 256) row4[i] = z;
    __syncthreads();
    int lo = (int)s_off[r], hi = (int)s_off[r + 1];
    for (int j = lo + t; j < hi; j += 256)
        S_out[(size_t)r * K_TOP + s_k[j]] = s_v[j];
}

// ---------------- A_new: one row per block, LDS accumulator, T-list streaming ----------------
__global__ __launch_bounds__(256) void k_anew(const unsigned* __restrict__ col_off,
                                              const unsigned* __restrict__ col_edges,
                                              const unsigned* __restrict__ rowA,
                                              const unsigned* __restrict__ dup,
                                              const float* __restrict__ score,
                                              const unsigned* __restrict__ perm_i,
                                              const unsigned* __restrict__ t_off,
                                              const unsigned* __restrict__ t_k,
                                              const float* __restrict__ t_v,
                                              float* __restrict__ A_out) {
    __shared__ float acc[K_TOP];
    int k1 = blockIdx.x, t = threadIdx.x;
    for (int i = t; i < K_TOP; i += 256) acc[i] = 0.f;
    __syncthreads();
    unsigned p = perm_i[k1];
    int lo = (int)col_off[p], hi = (int)col_off[p + 1];
    for (int i = lo; i < hi; i++) {
        unsigned e = col_edges[i];
        if (dup[e]) continue;
        float sc = score[e];
        unsigned n = rowA[e];
        unsigned tb = t_off[n], te = t_off[n + 1];
        for (unsigned j = tb + t; j < te; j += 256)
            atomicAdd(&acc[t_k[j]], sc * t_v[j]);
    }
    __syncthreads();
    float* outp = &A_out[(size_t)k1 * K_TOP];
    for (int i = t; i < K_TOP; i += 256) outp[i] = (i == k1) ? 0.f : acc[i];
}

// ---------------- x_out gather ----------------
__global__ __launch_bounds__(128) void k_xout(const float* __restrict__ x_new,
                                              const double* __restrict__ fitness,
                                              const unsigned* __restrict__ perm_i,
                                              float* __restrict__ xo) {
    int k = blockIdx.x, d = threadIdx.x;
    unsigned p = perm_i[k];
    xo[(size_t)k * D_DIM + d] = x_new[(size_t)p * D_DIM + d] * (float)fitness[p];
}

extern "C" void kernel_launch(void* const* d_in, const int* in_sizes, int n_in,
                              void* d_out, int out_size, void* d_ws, size_t ws_size,
                              hipStream_t stream) {
    const float* x        = (const float*)d_in[0];
    const int*   edge_src = (const int*)d_in[1];
    const int*   edge_off = (const int*)d_in[2];
    const float* W_lin    = (const float*)d_in[3];
    const float* b_lin    = (const float*)d_in[4];
    const float* w_att    = (const float*)d_in[5];
    const float* b_att    = (const float*)d_in[6];
    const float* w1       = (const float*)d_in[7];
    const float* b1       = (const float*)d_in[8];
    const float* w2       = (const float*)d_in[9];
    const float* w3       = (const float*)d_in[10];
    const float* b3       = (const float*)d_in[11];

    float* out = (float*)d_out;
    float* out_xout  = out;
    float* out_anew  = out + (size_t)K_TOP * D_DIM;
    float* out_perm  = out_anew + (size_t)K_TOP * K_TOP;
    float* out_sperm = out_perm + K_TOP;

    char* wp = (char*)d_ws;
    char* wend = wp + ws_size;
    auto alloc = [&](size_t bytes) -> void* {
        void* p = (void*)wp;
        wp += (bytes + 255) & ~(size_t)255;
        return p;
    };
    unsigned* rowA      = (unsigned*)alloc((size_t)M_EDGES * 4);
    unsigned* colA      = (unsigned*)alloc((size_t)M_EDGES * 4);
    unsigned* dup       = (unsigned*)alloc((size_t)M_EDGES * 4);
    double*   score_d   = (double*)alloc((size_t)M_EDGES * 8);
    float*    score     = (float*)alloc((size_t)M_EDGES * 4);
    unsigned* cnts      = (unsigned*)alloc((size_t)2 * N_NODES * 4);
    unsigned* col_cnt   = cnts;
    unsigned* row_cnt   = cnts + N_NODES;
    unsigned* col_off   = (unsigned*)alloc((size_t)(N_NODES + 1) * 4);
    unsigned* row_off   = (unsigned*)alloc((size_t)(N_NODES + 1) * 4);
    unsigned* col_cur   = (unsigned*)alloc((size_t)N_NODES * 4);
    unsigned* row_cur   = (unsigned*)alloc((size_t)N_NODES * 4);
    unsigned* col_edges = (unsigned*)alloc((size_t)M_EDGES * 4);
    unsigned* row_edges = (unsigned*)alloc((size_t)M_EDGES * 4);
    float*    x_new     = (float*)alloc((size_t)N_NODES * D_DIM * 4);
    double*   q_score   = (double*)alloc((size_t)N_NODES * 8);
    double*   k_score   = (double*)alloc((size_t)N_NODES * 8);
    double*   aV        = (double*)alloc((size_t)N_NODES * 8);
    double*   bV        = (double*)alloc((size_t)N_NODES * 8);
    double*   finV      = (double*)alloc((size_t)N_NODES * 8);
    double*   fitness   = (double*)alloc((size_t)N_NODES * 8);
    unsigned long long* keys_a = (unsigned long long*)alloc((size_t)N_NODES * 8);
    unsigned long long* keys_b = (unsigned long long*)alloc((size_t)N_NODES * 8);
    unsigned* perm_i    = (unsigned*)alloc((size_t)K_TOP * 4);
    int*      inv_k     = (int*)alloc((size_t)N_NODES * 4);
    unsigned* s_cnt     = (unsigned*)alloc((size_t)N_NODES * 4);
    unsigned* s_off     = (unsigned*)alloc((size_t)(N_NODES + 1) * 4);
    unsigned* s_k       = (unsigned*)alloc((size_t)M_EDGES * 4);
    float*    s_v       = (float*)alloc((size_t)M_EDGES * 4);
    unsigned* t_cnt     = (unsigned*)alloc((size_t)N_NODES * 4);
    unsigned* t_off     = (unsigned*)alloc((size_t)(N_NODES + 1) * 4);
    size_t remain = (size_t)(wend - wp);
    size_t tcap = remain / 8;
    if (tcap > (size_t)6 * 1024 * 1024) tcap = (size_t)6 * 1024 * 1024;
    unsigned* t_k = (unsigned*)alloc(tcap * 4);
    float*    t_v = (float*)alloc(tcap * 4);

    hipMemsetAsync(cnts, 0, (size_t)2 * N_NODES * 4, stream);

    k_init_edges<<<(M_EDGES + 255) / 256, 256, 0, stream>>>(edge_src, edge_off, rowA, colA, dup, col_cnt, row_cnt);
    k_scan2<<<2, 1024, 0, stream>>>(col_cnt, col_off, col_cur, row_cnt, row_off, row_cur);
    k_fill<<<(M_EDGES + 255) / 256, 256, 0, stream>>>(rowA, colA, col_cur, row_cur, col_edges, row_edges);
    k_lin<<<N_NODES, 128, 0, stream>>>(x, col_off, col_edges, rowA, dup, W_lin, b_lin, w_att, q_score, k_score);
    k_sm_xnew<<<N_NODES, 128, 0, stream>>>(x, col_off, col_edges, rowA, q_score, k_score, b_att,
                                           w1, b1, w2, w3, b3, score_d, score, x_new, aV, bV, finV);
    k_fitness<<<N_NODES, 64, 0, stream>>>(col_off, col_edges, rowA, aV, bV, finV, fitness);
    k_sortlocal<<<4, 1024, 0, stream>>>(fitness, keys_a);
    k_merge<<<N_NODES / 256, 256, 0, stream>>>(keys_a, keys_b, 2048);
    k_merge_emit<<<N_NODES / 256, 256, 0, stream>>>(keys_b, perm_i, inv_k, out_perm);
    k_scount<<<N_NODES, 64, 0, stream>>>(row_off, row_edges, colA, dup, inv_k, s_cnt);
    k_tcount<<<N_NODES, 64, 0, stream>>>(row_off, row_edges, colA, s_cnt, t_cnt);
    k_scan2<<<2, 1024, 0, stream>>>(s_cnt, s_off, (unsigned*)nullptr, t_cnt, t_off, (unsigned*)nullptr);
    k_sfill<<<N_NODES, 64, 0, stream>>>(row_off, row_edges, colA, dup, inv_k, s_off, score, s_k, s_v);
    k_tfill<<<N_NODES, 64, 0, stream>>>(row_off, row_edges, colA, s_off, s_cnt, s_k, s_v, t_off,
                                        t_k, t_v, (unsigned)tcap);
    k_spermz<<<N_NODES, 256, 0, stream>>>(s_off, s_k, s_v, out_sperm);
    k_anew<<<K_TOP, 256, 0, stream>>>(col_off, col_edges, rowA, dup, score, perm_i, t_off, t_k, t_v, out_anew);
    k_xout<<<K_TOP, 128, 0, stream>>>(x_new, fitness, perm_i, out_xout);
}